// Round 3
// baseline (750.514 us; speedup 1.0000x reference)
//
#include <hip/hip_runtime.h>

// TPF encoder, wave-autonomous MFMA fp16 version.
// Each wave owns 16 rows x 128 cols: A-frags gathered directly from global,
// LayerNorm wave-local (shfl_xor), layer->layer transpose via per-wave LDS.
// ZERO __syncthreads in the hot kernels.
//
//  - MFMA 16x16x32_f16, fp32 accum. acc[8] f32x4 = rows q*4+r, cols ct*16+n15.
//  - Wp packed per launch: Wp[kb*4096 + n*32 + kk] = fp16(W[kb*32+kk][n]);
//    B-frag = one 16B load/lane.
//  - Transpose buffer stride 136 fp16 (272B row): ds_read_b128 A-frags hit all
//    32 banks uniformly (8 accesses/bank = minimum for 256 dwords).
//  - segment-sum: fp32 atomicAdd (device scope); agg zeroed via hipMemsetAsync.
//  - h1 intermediate fp16 (halves iter-1 gather bytes).

#define D    128
#define TSTR 136

typedef float    f32x4 __attribute__((ext_vector_type(4)));
typedef _Float16 f16x8 __attribute__((ext_vector_type(8)));

__device__ __forceinline__ void lds_fence() {
    asm volatile("s_waitcnt lgkmcnt(0)" ::: "memory");
}

__device__ __forceinline__ f16x8 cvt8(const float* __restrict__ p) {
    float4 a = *(const float4*)p;
    float4 b = *(const float4*)(p + 4);
    f16x8 r = { (_Float16)a.x, (_Float16)a.y, (_Float16)a.z, (_Float16)a.w,
                (_Float16)b.x, (_Float16)b.y, (_Float16)b.z, (_Float16)b.w };
    return r;
}

__device__ __forceinline__ unsigned short f2h(float f) {
    union { _Float16 h; unsigned short u; } x;
    x.h = (_Float16)f;
    return x.u;
}

// ---- weight pack: Wp[kb*4096 + n*32 + kk] = fp16(W[kb*32+kk][n]) per matrix,level ----
__global__ __launch_bounds__(256) void pack_w(
    const float* __restrict__ brW1, const float* __restrict__ brW2,
    const float* __restrict__ sW1,  const float* __restrict__ sW2,
    const float* __restrict__ hW,   unsigned short* __restrict__ Wp)
{
    int p = blockIdx.x * 256 + threadIdx.x;   // 0 .. 262143
    const float* src; int off, K;
    if (p < 65536)       { src = brW1; off = 0;      K = 256; }
    else if (p < 98304)  { src = brW2; off = 65536;  K = 128; }
    else if (p < 163840) { src = sW1;  off = 98304;  K = 256; }
    else if (p < 196608) { src = sW2;  off = 163840; K = 128; }
    else                 { src = hW;   off = 196608; K = 256; }
    int q = p - off, lvl, r;
    if (K == 256) { lvl = q >> 15; r = q & 32767; }
    else          { lvl = q >> 14; r = q & 16383; }
    int kb = r >> 12, n = (r >> 5) & 127, kk = r & 31;
    Wp[p] = f2h(src[(size_t)lvl * K * 128 + (size_t)(kb * 32 + kk) * 128 + n]);
}

// bias + LayerNorm + relu, wave-local. acc[ct][r]: row q*4+r, col ct*16+n15.
__device__ __forceinline__ void ln_relu_wave(f32x4 acc[8],
    const float* __restrict__ b, const float* __restrict__ g,
    const float* __restrict__ be, int n15, int q)
{
#pragma unroll
    for (int ct = 0; ct < 8; ++ct) {
        float bb = b[ct * 16 + n15];
#pragma unroll
        for (int r = 0; r < 4; ++r) acc[ct][r] += bb;
    }
    float sum[4] = {0,0,0,0}, ss[4] = {0,0,0,0};
#pragma unroll
    for (int ct = 0; ct < 8; ++ct)
#pragma unroll
        for (int r = 0; r < 4; ++r) {
            sum[r] += acc[ct][r];
            ss[r]  += acc[ct][r] * acc[ct][r];
        }
#pragma unroll
    for (int off = 1; off < 16; off <<= 1)
#pragma unroll
        for (int r = 0; r < 4; ++r) {
            sum[r] += __shfl_xor(sum[r], off, 64);
            ss[r]  += __shfl_xor(ss[r],  off, 64);
        }
    float mean[4], rs[4];
#pragma unroll
    for (int r = 0; r < 4; ++r) {
        mean[r] = sum[r] * (1.f / 128.f);
        float var = ss[r] * (1.f / 128.f) - mean[r] * mean[r];
        rs[r] = rsqrtf(var + 1e-5f);
    }
#pragma unroll
    for (int ct = 0; ct < 8; ++ct) {
        float gg = g[ct * 16 + n15], bb = be[ct * 16 + n15];
#pragma unroll
        for (int r = 0; r < 4; ++r)
            acc[ct][r] = fmaxf((acc[ct][r] - mean[r]) * rs[r] * gg + bb, 0.f);
    }
}

template<bool HF16>
__global__ __launch_bounds__(256, 4) void edge_mlp(
    const void* __restrict__ hsrc, const float* __restrict__ bond,
    const int* __restrict__ src, const int* __restrict__ dst,
    const unsigned short* __restrict__ Wp1, const unsigned short* __restrict__ Wp2,
    const float* __restrict__ b1, const float* __restrict__ g1, const float* __restrict__ be1,
    const float* __restrict__ b2, const float* __restrict__ g2, const float* __restrict__ be2,
    float* __restrict__ agg, int E)
{
    __shared__ _Float16 s_t[4][16 * TSTR];
    int t = threadIdx.x, w = t >> 6, l = t & 63, n15 = l & 15, q = l >> 4;
    int e0 = blockIdx.x * 64 + w * 16;           // E divisible by 64 for both levels
    _Float16* st = s_t[w];

    int srowA = src[e0 + n15];

    f32x4 acc[8];
#pragma unroll
    for (int ct = 0; ct < 8; ++ct) acc[ct] = (f32x4){0.f, 0.f, 0.f, 0.f};

#pragma unroll
    for (int kb = 0; kb < 8; ++kb) {
        f16x8 af;
        if (kb < 4) {
            if (HF16)
                af = *(const f16x8*)((const _Float16*)hsrc + (size_t)srowA * 128 + kb * 32 + q * 8);
            else
                af = cvt8((const float*)hsrc + (size_t)srowA * 128 + kb * 32 + q * 8);
        } else {
            af = cvt8(bond + (size_t)(e0 + n15) * 128 + (kb - 4) * 32 + q * 8);
        }
        const unsigned short* wb = Wp1 + (size_t)kb * 4096 + q * 8;
#pragma unroll
        for (int ct = 0; ct < 8; ++ct) {
            f16x8 bf = *(const f16x8*)(wb + (ct * 16 + n15) * 32);
            acc[ct] = __builtin_amdgcn_mfma_f32_16x16x32_f16(af, bf, acc[ct], 0, 0, 0);
        }
    }
    ln_relu_wave(acc, b1, g1, be1, n15, q);

#pragma unroll
    for (int ct = 0; ct < 8; ++ct)
#pragma unroll
        for (int r = 0; r < 4; ++r)
            st[(q * 4 + r) * TSTR + ct * 16 + n15] = (_Float16)acc[ct][r];
    lds_fence();

    f32x4 acc2[8];
#pragma unroll
    for (int ct = 0; ct < 8; ++ct) acc2[ct] = (f32x4){0.f, 0.f, 0.f, 0.f};
#pragma unroll
    for (int kb = 0; kb < 4; ++kb) {
        f16x8 af = *(const f16x8*)(st + n15 * TSTR + kb * 32 + q * 8);
        const unsigned short* wb = Wp2 + (size_t)kb * 4096 + q * 8;
#pragma unroll
        for (int ct = 0; ct < 8; ++ct) {
            f16x8 bf = *(const f16x8*)(wb + (ct * 16 + n15) * 32);
            acc2[ct] = __builtin_amdgcn_mfma_f32_16x16x32_f16(af, bf, acc2[ct], 0, 0, 0);
        }
    }
    ln_relu_wave(acc2, b2, g2, be2, n15, q);

    int dr[4];
#pragma unroll
    for (int r = 0; r < 4; ++r) dr[r] = dst[e0 + q * 4 + r];
#pragma unroll
    for (int ct = 0; ct < 8; ++ct)
#pragma unroll
        for (int r = 0; r < 4; ++r)
            atomicAdd(agg + (size_t)dr[r] * D + ct * 16 + n15, acc2[ct][r]);
}

template<bool OUT_F16>
__global__ __launch_bounds__(256, 4) void node_mlp(
    const float* __restrict__ ax, const float* __restrict__ agg,
    const unsigned short* __restrict__ Wp1, const unsigned short* __restrict__ Wp2,
    const unsigned short* __restrict__ Wp3,
    const float* __restrict__ b1, const float* __restrict__ g1, const float* __restrict__ be1,
    const float* __restrict__ b2, const float* __restrict__ g2, const float* __restrict__ be2,
    const float* __restrict__ b3, const float* __restrict__ g3, const float* __restrict__ be3,
    void* __restrict__ out, int N)
{
    __shared__ _Float16 s_t[4][16 * TSTR];
    __shared__ _Float16 s_ax[4][4 * 64 * 8];   // frag-linear [kb][lane][8]
    int t = threadIdx.x, w = t >> 6, l = t & 63, n15 = l & 15, q = l >> 4;
    int nb = blockIdx.x * 64 + w * 16;
    _Float16* st = s_t[w];
    _Float16* sx = s_ax[w];

    int rA = nb + n15; if (rA >= N) rA = N - 1;   // clamp for tail blocks

    f32x4 acc[8];
#pragma unroll
    for (int ct = 0; ct < 8; ++ct) acc[ct] = (f32x4){0.f, 0.f, 0.f, 0.f};

#pragma unroll
    for (int kb = 0; kb < 8; ++kb) {
        f16x8 af;
        if (kb < 4) {
            af = cvt8(ax + (size_t)rA * 128 + kb * 32 + q * 8);
            *(f16x8*)(sx + (kb * 64 + l) * 8) = af;   // stash for head layer
        } else {
            af = cvt8(agg + (size_t)rA * 128 + (kb - 4) * 32 + q * 8);
        }
        const unsigned short* wb = Wp1 + (size_t)kb * 4096 + q * 8;
#pragma unroll
        for (int ct = 0; ct < 8; ++ct) {
            f16x8 bf = *(const f16x8*)(wb + (ct * 16 + n15) * 32);
            acc[ct] = __builtin_amdgcn_mfma_f32_16x16x32_f16(af, bf, acc[ct], 0, 0, 0);
        }
    }
    ln_relu_wave(acc, b1, g1, be1, n15, q);

#pragma unroll
    for (int ct = 0; ct < 8; ++ct)
#pragma unroll
        for (int r = 0; r < 4; ++r)
            st[(q * 4 + r) * TSTR + ct * 16 + n15] = (_Float16)acc[ct][r];
    lds_fence();

    f32x4 acc2[8];
#pragma unroll
    for (int ct = 0; ct < 8; ++ct) acc2[ct] = (f32x4){0.f, 0.f, 0.f, 0.f};
#pragma unroll
    for (int kb = 0; kb < 4; ++kb) {
        f16x8 af = *(const f16x8*)(st + n15 * TSTR + kb * 32 + q * 8);
        const unsigned short* wb = Wp2 + (size_t)kb * 4096 + q * 8;
#pragma unroll
        for (int ct = 0; ct < 8; ++ct) {
            f16x8 bf = *(const f16x8*)(wb + (ct * 16 + n15) * 32);
            acc2[ct] = __builtin_amdgcn_mfma_f32_16x16x32_f16(af, bf, acc2[ct], 0, 0, 0);
        }
    }
    ln_relu_wave(acc2, b2, g2, be2, n15, q);
    lds_fence();   // layer-2 reads of s_t complete before overwrite (WAR)

#pragma unroll
    for (int ct = 0; ct < 8; ++ct)       // f2 -> s_t (head input cols 128..255)
#pragma unroll
        for (int r = 0; r < 4; ++r)
            st[(q * 4 + r) * TSTR + ct * 16 + n15] = (_Float16)acc2[ct][r];
    lds_fence();

    f32x4 acc3[8];
#pragma unroll
    for (int ct = 0; ct < 8; ++ct) acc3[ct] = (f32x4){0.f, 0.f, 0.f, 0.f};
#pragma unroll
    for (int kb = 0; kb < 8; ++kb) {
        f16x8 af;
        if (kb < 4) af = *(const f16x8*)(sx + (kb * 64 + l) * 8);
        else        af = *(const f16x8*)(st + n15 * TSTR + (kb - 4) * 32 + q * 8);
        const unsigned short* wb = Wp3 + (size_t)kb * 4096 + q * 8;
#pragma unroll
        for (int ct = 0; ct < 8; ++ct) {
            f16x8 bf = *(const f16x8*)(wb + (ct * 16 + n15) * 32);
            acc3[ct] = __builtin_amdgcn_mfma_f32_16x16x32_f16(af, bf, acc3[ct], 0, 0, 0);
        }
    }
    ln_relu_wave(acc3, b3, g3, be3, n15, q);

#pragma unroll
    for (int ct = 0; ct < 8; ++ct)
#pragma unroll
        for (int r = 0; r < 4; ++r) {
            int gr = nb + q * 4 + r;
            int col = ct * 16 + n15;
            if (gr < N) {
                if (OUT_F16)
                    ((_Float16*)out)[(size_t)gr * D + col] = (_Float16)acc3[ct][r];
                else
                    ((float*)out)[(size_t)gr * D + col] = acc3[ct][r];
            }
        }
}

extern "C" void kernel_launch(void* const* d_in, const int* in_sizes, int n_in,
                              void* d_out, int out_size, void* d_ws, size_t ws_size,
                              hipStream_t stream)
{
    const float* h2   = (const float*)d_in[0];
    const float* ax1  = (const float*)d_in[1];
    const float* ax0  = (const float*)d_in[2];
    const float* bx2  = (const float*)d_in[3];
    const float* bx1  = (const float*)d_in[4];
    const float* brW1 = (const float*)d_in[5];
    const float* brb1 = (const float*)d_in[6];
    const float* brg1 = (const float*)d_in[7];
    const float* brbe1= (const float*)d_in[8];
    const float* brW2 = (const float*)d_in[9];
    const float* brb2 = (const float*)d_in[10];
    const float* brg2 = (const float*)d_in[11];
    const float* brbe2= (const float*)d_in[12];
    const float* sW1  = (const float*)d_in[13];
    const float* sb1  = (const float*)d_in[14];
    const float* sg1  = (const float*)d_in[15];
    const float* sbe1 = (const float*)d_in[16];
    const float* sW2  = (const float*)d_in[17];
    const float* sb2  = (const float*)d_in[18];
    const float* sg2  = (const float*)d_in[19];
    const float* sbe2 = (const float*)d_in[20];
    const float* hW   = (const float*)d_in[21];
    const float* hb   = (const float*)d_in[22];
    const float* hg   = (const float*)d_in[23];
    const float* hbe  = (const float*)d_in[24];
    const int*   src2 = (const int*)d_in[25];
    const int*   dst2 = (const int*)d_in[26];
    const int*   src1 = (const int*)d_in[27];
    const int*   dst1 = (const int*)d_in[28];

    int n2 = in_sizes[0] / D;
    int n1 = in_sizes[1] / D;
    int n0 = in_sizes[2] / D;

    unsigned short* Wp  = (unsigned short*)d_ws;          // 512 KB
    float*          agg = (float*)((char*)d_ws + 524288); // n1*128 fp32 (reused for n0)
    _Float16*       h1  = (_Float16*)(agg + (size_t)n1 * D);

    const unsigned short* pBr1[2] = { Wp + 0,      Wp + 32768 };
    const unsigned short* pBr2[2] = { Wp + 65536,  Wp + 65536  + 16384 };
    const unsigned short* pS1 [2] = { Wp + 98304,  Wp + 98304  + 32768 };
    const unsigned short* pS2 [2] = { Wp + 163840, Wp + 163840 + 16384 };
    const unsigned short* pH  [2] = { Wp + 196608, Wp + 196608 + 32768 };

    pack_w<<<dim3(1024), dim3(256), 0, stream>>>(brW1, brW2, sW1, sW2, hW, Wp);

    // ---- iteration 0 (level 2 -> 1) ----
    hipMemsetAsync(agg, 0, (size_t)n1 * D * sizeof(float), stream);
    edge_mlp<false><<<dim3(n2 / 64), dim3(256), 0, stream>>>(
        h2, bx2, src2, dst2, pBr1[0], pBr2[0],
        brb1, brg1, brbe1, brb2, brg2, brbe2, agg, n2);
    node_mlp<true><<<dim3((n1 + 63) / 64), dim3(256), 0, stream>>>(
        ax1, agg, pS1[0], pS2[0], pH[0],
        sb1, sg1, sbe1, sb2, sg2, sbe2, hb, hg, hbe, h1, n1);

    // ---- iteration 1 (level 1 -> 0) ----
    hipMemsetAsync(agg, 0, (size_t)n0 * D * sizeof(float), stream);
    edge_mlp<true><<<dim3(n1 / 64), dim3(256), 0, stream>>>(
        h1, bx1, src1, dst1, pBr1[1], pBr2[1],
        brb1 + D, brg1 + D, brbe1 + D, brb2 + D, brg2 + D, brbe2 + D, agg, n1);
    node_mlp<false><<<dim3((n0 + 63) / 64), dim3(256), 0, stream>>>(
        ax0, agg, pS1[1], pS2[1], pH[1],
        sb1 + D, sg1 + D, sbe1 + D, sb2 + D, sg2 + D, sbe2 + D,
        hb + D, hg + D, hbe + D, d_out, n0);
}